// Round 2
// baseline (880.727 us; speedup 1.0000x reference)
//
#include <hip/hip_runtime.h>

// GCN 2-layer forward, fp32, atomic scatter-add baseline.
// NOTE: harness delivers integer inputs as int32 (edge_index int64 -> int*).
// Pipeline: deg -> dinv -> h1=x@W1 -> scatter(h1,norm) -> +b1,relu
//           -> h2=hr@W2 -> scatter(h2,norm) into d_out -> +b2, out[N*16]=0.

__global__ void deg_kernel(const int* __restrict__ col, int* __restrict__ deg, int E) {
    int e = blockIdx.x * blockDim.x + threadIdx.x;
    if (e < E) atomicAdd(&deg[col[e]], 1);
}

__global__ void dinv_kernel(const int* __restrict__ deg, float* __restrict__ dinv, int n) {
    int i = blockIdx.x * blockDim.x + threadIdx.x;
    if (i < n) {
        int d = deg[i];
        dinv[i] = (d > 0) ? rsqrtf((float)d) : 0.f;
    }
}

// h[n, 0:OUTC] = x[n, 0:INC] @ W[INC, OUTC]; W staged in LDS; OUTC lanes per node.
template <int INC, int OUTC>
__global__ void dense_kernel(const float* __restrict__ x, const float* __restrict__ W,
                             float* __restrict__ h, int n) {
    __shared__ float Wl[INC * OUTC];
    for (int i = threadIdx.x; i < INC * OUTC; i += blockDim.x) Wl[i] = W[i];
    __syncthreads();
    const int npb  = blockDim.x / OUTC;          // nodes per block-iteration
    const int j    = threadIdx.x % OUTC;
    const int slot = threadIdx.x / OUTC;
    for (int node = blockIdx.x * npb + slot; node < n; node += gridDim.x * npb) {
        const float4* xr = (const float4*)(x + (size_t)node * INC);
        float acc = 0.f;
#pragma unroll
        for (int k4 = 0; k4 < INC / 4; ++k4) {
            float4 v = xr[k4];
            acc = fmaf(v.x, Wl[(k4 * 4 + 0) * OUTC + j], acc);
            acc = fmaf(v.y, Wl[(k4 * 4 + 1) * OUTC + j], acc);
            acc = fmaf(v.z, Wl[(k4 * 4 + 2) * OUTC + j], acc);
            acc = fmaf(v.w, Wl[(k4 * 4 + 3) * OUTC + j], acc);
        }
        h[(size_t)node * OUTC + j] = acc;
    }
}

// One C-lane group per edge: out[col[e], j] += h[row[e], j] * dinv[row]*dinv[col]
template <int C>
__global__ void aggregate_kernel(const int* __restrict__ row,
                                 const int* __restrict__ col,
                                 const float* __restrict__ dinv,
                                 const float* __restrict__ h,
                                 float* __restrict__ out, int E) {
    unsigned gid = blockIdx.x * blockDim.x + threadIdx.x;
    unsigned e = gid / C;
    unsigned j = gid % C;
    if (e >= (unsigned)E) return;
    int r = row[e];
    int c = col[e];
    float nrm = dinv[r] * dinv[c];
    atomicAdd(&out[(size_t)c * C + j], h[(size_t)r * C + j] * nrm);
}

template <int C>
__global__ void bias_relu_kernel(const float* __restrict__ in, const float* __restrict__ b,
                                 float* __restrict__ outp, int total) {
    int i = blockIdx.x * blockDim.x + threadIdx.x;
    if (i < total) {
        float v = in[i] + b[i % C];
        outp[i] = v > 0.f ? v : 0.f;
    }
}

template <int C>
__global__ void bias_final_kernel(float* __restrict__ out, const float* __restrict__ b,
                                  int total, int out_size) {
    int i = blockIdx.x * blockDim.x + threadIdx.x;
    if (i < total) out[i] += b[i % C];
    if (i == 0 && total < out_size) out[total] = 0.f;  // second tuple output: scalar 0
}

extern "C" void kernel_launch(void* const* d_in, const int* in_sizes, int n_in,
                              void* d_out, int out_size, void* d_ws, size_t ws_size,
                              hipStream_t stream) {
    const float* x  = (const float*)d_in[0];
    const int*   ei = (const int*)d_in[1];    // harness converts int64 -> int32
    const float* W1 = (const float*)d_in[2];
    const float* b1 = (const float*)d_in[3];
    const float* W2 = (const float*)d_in[4];
    const float* b2 = (const float*)d_in[5];

    const int IN_C = 128, HID = 32, OC = 16;
    const int N = in_sizes[0] / IN_C;       // 100000
    const int E = in_sizes[1] / 2;          // 3200000
    const int* row = ei;
    const int* col = ei + E;

    // workspace carve-up (256B-aligned); total ~26.4 MB
    char* base = (char*)d_ws;
    size_t off = 0;
    auto carve = [&](size_t bytes) -> char* {
        char* p = base + off;
        off = (off + bytes + 255) & ~(size_t)255;
        return p;
    };
    int*   deg  = (int*)  carve((size_t)N * 4);
    float* dinv = (float*)carve((size_t)N * 4);
    float* h1   = (float*)carve((size_t)N * HID * 4);  // reused as h_relu
    float* o1   = (float*)carve((size_t)N * HID * 4);  // reused as h2 (N*OC)
    (void)ws_size; (void)n_in;

    float* outp = (float*)d_out;

    // 1) degree
    hipMemsetAsync(deg, 0, (size_t)N * 4, stream);
    deg_kernel<<<(E + 255) / 256, 256, 0, stream>>>(col, deg, E);
    // 2) dinv
    dinv_kernel<<<(N + 255) / 256, 256, 0, stream>>>(deg, dinv, N);
    // 3) h1 = x @ W1
    dense_kernel<128, 32><<<2048, 256, 0, stream>>>(x, W1, h1, N);
    // 4) o1 = scatter_add(h1[row]*norm -> col)
    hipMemsetAsync(o1, 0, (size_t)N * HID * 4, stream);
    {
        long long threads = (long long)E * HID;
        aggregate_kernel<32><<<(unsigned)((threads + 255) / 256), 256, 0, stream>>>(
            row, col, dinv, h1, o1, E);
    }
    // 5) h_relu = relu(o1 + b1)  (into h1 buffer)
    bias_relu_kernel<32><<<(N * HID + 255) / 256, 256, 0, stream>>>(o1, b1, h1, N * HID);
    // 6) h2 = h_relu @ W2  (into o1 buffer)
    dense_kernel<32, 16><<<2048, 256, 0, stream>>>(h1, W2, o1, N);
    // 7) d_out = scatter_add(h2[row]*norm -> col)
    hipMemsetAsync(outp, 0, (size_t)out_size * 4, stream);
    {
        long long threads = (long long)E * OC;
        aggregate_kernel<16><<<(unsigned)((threads + 255) / 256), 256, 0, stream>>>(
            row, col, dinv, o1, outp, E);
    }
    // 8) += b2; trailing scalar output = 0
    bias_final_kernel<16><<<(N * OC + 255) / 256, 256, 0, stream>>>(outp, b2, N * OC, out_size);
}

// Round 3
// 812.960 us; speedup vs baseline: 1.0834x; 1.0834x over previous
//
#include <hip/hip_runtime.h>

// GCN 2-layer forward, fp32. CSR pull-aggregation (no float atomics).
// Round-2 evidence: fp32 atomicAdd writes through TCC (WRITE_SIZE == E*C*4
// exactly), so scatter-atomics cost ~50x the ideal write traffic. This
// version sorts edges by target (counting sort) once per call, then each
// layer pulls: one wave per node, register accumulation, single write.

#define WAVE 64

__global__ void deg_kernel(const int* __restrict__ col, int* __restrict__ deg, int E) {
    int e = blockIdx.x * blockDim.x + threadIdx.x;
    if (e < E) atomicAdd(&deg[col[e]], 1);
}

__global__ void dinv_kernel(const int* __restrict__ deg, float* __restrict__ dinv, int n) {
    int i = blockIdx.x * blockDim.x + threadIdx.x;
    if (i < n) {
        int d = deg[i];
        dinv[i] = (d > 0) ? rsqrtf((float)d) : 0.f;
    }
}

// --- 3-phase exclusive scan of deg[n] -> rowptr[n+1] (+ cursor copy) ---
__global__ void scan_block_kernel(const int* __restrict__ deg, int* __restrict__ excl,
                                  int* __restrict__ blocksum, int n) {
    __shared__ int tmp[256];
    int i = blockIdx.x * 256 + threadIdx.x;
    int v = (i < n) ? deg[i] : 0;
    tmp[threadIdx.x] = v;
    __syncthreads();
    for (int off = 1; off < 256; off <<= 1) {
        int t = (threadIdx.x >= off) ? tmp[threadIdx.x - off] : 0;
        __syncthreads();
        tmp[threadIdx.x] += t;
        __syncthreads();
    }
    if (i < n) excl[i] = tmp[threadIdx.x] - v;  // exclusive within block
    if (threadIdx.x == 255) blocksum[blockIdx.x] = tmp[255];
}

__global__ void scan_sums_kernel(int* __restrict__ blocksum, int nb) {
    // nb <= 512 (N up to 131072)
    __shared__ int tmp[512];
    int tid = threadIdx.x;
    int v = (tid < nb) ? blocksum[tid] : 0;
    tmp[tid] = v;
    __syncthreads();
    for (int off = 1; off < 512; off <<= 1) {
        int t = (tid >= off) ? tmp[tid - off] : 0;
        __syncthreads();
        tmp[tid] += t;
        __syncthreads();
    }
    if (tid < nb) blocksum[tid] = tmp[tid] - v;  // exclusive block offsets
}

__global__ void finalize_rowptr_kernel(const int* __restrict__ excl,
                                       const int* __restrict__ blockoff,
                                       int* __restrict__ rowptr, int* __restrict__ cursor,
                                       int n, int E) {
    int i = blockIdx.x * 256 + threadIdx.x;
    if (i < n) {
        int v = excl[i] + blockoff[blockIdx.x];
        rowptr[i] = v;
        cursor[i] = v;
    }
    if (i == 0) rowptr[n] = E;
}

// Bucket-fill: place (src, norm) of each edge at its sorted-by-col slot.
__global__ void fill_kernel(const int* __restrict__ row, const int* __restrict__ col,
                            const float* __restrict__ dinv, int* __restrict__ cursor,
                            int* __restrict__ srcs, float* __restrict__ nrms, int E) {
    int e = blockIdx.x * blockDim.x + threadIdx.x;
    if (e >= E) return;
    int r = row[e], c = col[e];
    int pos = atomicAdd(&cursor[c], 1);
    srcs[pos] = r;
    nrms[pos] = dinv[r] * dinv[c];
}

// h[n, 0:OUTC] = x[n, 0:INC] @ W[INC, OUTC]; W staged in LDS; OUTC lanes/node.
template <int INC, int OUTC>
__global__ void dense_kernel(const float* __restrict__ x, const float* __restrict__ W,
                             float* __restrict__ h, int n) {
    __shared__ float Wl[INC * OUTC];
    for (int i = threadIdx.x; i < INC * OUTC; i += blockDim.x) Wl[i] = W[i];
    __syncthreads();
    const int npb  = blockDim.x / OUTC;
    const int j    = threadIdx.x % OUTC;
    const int slot = threadIdx.x / OUTC;
    for (int node = blockIdx.x * npb + slot; node < n; node += gridDim.x * npb) {
        const float4* xr = (const float4*)(x + (size_t)node * INC);
        float acc = 0.f;
#pragma unroll
        for (int k4 = 0; k4 < INC / 4; ++k4) {
            float4 v = xr[k4];
            acc = fmaf(v.x, Wl[(k4 * 4 + 0) * OUTC + j], acc);
            acc = fmaf(v.y, Wl[(k4 * 4 + 1) * OUTC + j], acc);
            acc = fmaf(v.z, Wl[(k4 * 4 + 2) * OUTC + j], acc);
            acc = fmaf(v.w, Wl[(k4 * 4 + 3) * OUTC + j], acc);
        }
        h[(size_t)node * OUTC + j] = acc;
    }
}

// One wave per target node: acc[j] = sum_k h[srcs[k], j] * nrms[k]; fused bias(/relu).
template <int C, bool RELU>
__global__ void csr_agg_kernel(const int* __restrict__ rowptr,
                               const int* __restrict__ srcs,
                               const float* __restrict__ nrms,
                               const float* __restrict__ h,
                               const float* __restrict__ bias,
                               float* __restrict__ out, int n) {
    const int EPI = WAVE / C;  // edges in flight per wave
    int node = (int)((blockIdx.x * (unsigned)blockDim.x + threadIdx.x) / WAVE);
    int lane = threadIdx.x & (WAVE - 1);
    int j  = lane & (C - 1);
    int eo = lane / C;
    if (node >= n) return;
    int start = rowptr[node], end = rowptr[node + 1];
    float acc = 0.f;
    for (int k = start + eo; k < end; k += EPI) {
        int s = srcs[k];
        float w = nrms[k];
        acc = fmaf(h[(size_t)s * C + j], w, acc);
    }
#pragma unroll
    for (int off = C; off < WAVE; off <<= 1)
        acc += __shfl_xor(acc, off, WAVE);
    if (eo == 0) {
        float v = acc + bias[j];
        if (RELU) v = v > 0.f ? v : 0.f;
        out[(size_t)node * C + j] = v;
    }
}

__global__ void tail_kernel(float* __restrict__ out, int idx) {
    if (blockIdx.x == 0 && threadIdx.x == 0) out[idx] = 0.f;
}

extern "C" void kernel_launch(void* const* d_in, const int* in_sizes, int n_in,
                              void* d_out, int out_size, void* d_ws, size_t ws_size,
                              hipStream_t stream) {
    const float* x  = (const float*)d_in[0];
    const int*   ei = (const int*)d_in[1];    // harness converts int64 -> int32
    const float* W1 = (const float*)d_in[2];
    const float* b1 = (const float*)d_in[3];
    const float* W2 = (const float*)d_in[4];
    const float* b2 = (const float*)d_in[5];

    const int IN_C = 128, HID = 32, OC = 16;
    const int N = in_sizes[0] / IN_C;       // 100000
    const int E = in_sizes[1] / 2;          // 3200000
    const int* row = ei;
    const int* col = ei + E;

    char* base = (char*)d_ws;
    size_t off = 0;
    auto carve = [&](size_t bytes) -> char* {
        char* p = base + off;
        off = (off + bytes + 255) & ~(size_t)255;
        return p;
    };
    int*   deg      = (int*)  carve((size_t)N * 4);
    float* dinv     = (float*)carve((size_t)N * 4);
    int*   excl     = (int*)  carve((size_t)N * 4);
    int*   rowptr   = (int*)  carve((size_t)(N + 1) * 4);
    int*   cursor   = (int*)  carve((size_t)N * 4);
    int*   blocksum = (int*)  carve(512 * 4);
    int*   srcs     = (int*)  carve((size_t)E * 4);
    float* nrms     = (float*)carve((size_t)E * 4);
    float* bufA     = (float*)carve((size_t)N * HID * 4);  // h1, then h2
    float* bufB     = (float*)carve((size_t)N * HID * 4);  // h_relu
    (void)ws_size; (void)n_in;

    float* outp = (float*)d_out;

    const int scan_blocks = (N + 255) / 256;  // 391 <= 512

    // CSR build
    hipMemsetAsync(deg, 0, (size_t)N * 4, stream);
    deg_kernel<<<(E + 255) / 256, 256, 0, stream>>>(col, deg, E);
    dinv_kernel<<<(N + 255) / 256, 256, 0, stream>>>(deg, dinv, N);
    scan_block_kernel<<<scan_blocks, 256, 0, stream>>>(deg, excl, blocksum, N);
    scan_sums_kernel<<<1, 512, 0, stream>>>(blocksum, scan_blocks);
    finalize_rowptr_kernel<<<scan_blocks, 256, 0, stream>>>(excl, blocksum, rowptr, cursor, N, E);
    fill_kernel<<<(E + 255) / 256, 256, 0, stream>>>(row, col, dinv, cursor, srcs, nrms, E);

    // Layer 1: h1 = x@W1 ; hr = relu(agg(h1) + b1)
    dense_kernel<128, 32><<<2048, 256, 0, stream>>>(x, W1, bufA, N);
    {
        int nodes_per_block = 256 / WAVE;  // 4
        int grid = (N + nodes_per_block - 1) / nodes_per_block;
        csr_agg_kernel<32, true><<<grid, 256, 0, stream>>>(rowptr, srcs, nrms, bufA, b1, bufB, N);
    }
    // Layer 2: h2 = hr@W2 ; out = agg(h2) + b2
    dense_kernel<32, 16><<<2048, 256, 0, stream>>>(bufB, W2, bufA, N);
    {
        int nodes_per_block = 256 / WAVE;
        int grid = (N + nodes_per_block - 1) / nodes_per_block;
        csr_agg_kernel<16, false><<<grid, 256, 0, stream>>>(rowptr, srcs, nrms, bufA, b2, outp, N);
    }
    if (out_size > N * OC)
        tail_kernel<<<1, 64, 0, stream>>>(outp, N * OC);
}